// Round 9
// baseline (957.295 us; speedup 1.0000x reference)
//
#include <hip/hip_runtime.h>

#define NN 40000      // nodes
#define NE 640000     // edges
#define DD 128        // feature dim
#define NG 64         // graphs

typedef float vf4 __attribute__((ext_vector_type(4)));
typedef unsigned short us4 __attribute__((ext_vector_type(4)));
typedef unsigned short us8 __attribute__((ext_vector_type(8)));
typedef short bf16x8 __attribute__((ext_vector_type(8)));
typedef float f32x4 __attribute__((ext_vector_type(4)));

__device__ inline unsigned short f2bf(float f) {        // round-nearest-even
    unsigned int u = __float_as_uint(f);
    return (unsigned short)((u + 0x7fffu + ((u >> 16) & 1u)) >> 16);
}
__device__ inline float bf2f(unsigned short s) {
    return __uint_as_float((unsigned int)s << 16);
}

// ---------------------------------------------------------------------------
// Fused preamble: x->bf16 | weight split | dst histogram.
// (No batch histogram — that was R6's 221 µs atomic storm; counts come from
// the binary-search block in scan_k.)
// ---------------------------------------------------------------------------
#define PRE_CVT_BLKS  2500
#define PRE_W_BLKS    512
#define PRE_H_BLKS    2500
#define PRE_BLOCKS    (PRE_CVT_BLKS + PRE_W_BLKS + PRE_H_BLKS)

template <int USE_BF>
__global__ __launch_bounds__(256) void preamble_k(
    const float* __restrict__ x, unsigned short* __restrict__ hB,
    const float* __restrict__ m0, const float* __restrict__ m1,
    const float* __restrict__ m2, const float* __restrict__ m3,
    const float* __restrict__ m4, const float* __restrict__ m5,
    const float* __restrict__ m6, const float* __restrict__ m7,
    unsigned short* __restrict__ whi, unsigned short* __restrict__ wlo,
    const int* __restrict__ dst, int* __restrict__ cnt)
{
    const int bid = blockIdx.x;
    if (bid < PRE_CVT_BLKS) {
        if (!USE_BF) return;
        size_t i = ((size_t)bid * 256 + threadIdx.x) * 8;   // exact cover
        vf4 a = __builtin_nontemporal_load((const vf4*)(x + i));
        vf4 b = __builtin_nontemporal_load((const vf4*)(x + i + 4));
        us4 o0 = {f2bf(a.x), f2bf(a.y), f2bf(a.z), f2bf(a.w)};
        us4 o1 = {f2bf(b.x), f2bf(b.y), f2bf(b.z), f2bf(b.w)};
        *(us4*)(hB + i) = o0;
        *(us4*)(hB + i + 4) = o1;
    } else if (bid < PRE_CVT_BLKS + PRE_W_BLKS) {
        const float* ms[8] = {m0, m1, m2, m3, m4, m5, m6, m7};
        int b = bid - PRE_CVT_BLKS;
        int mat = b >> 6;                        // 64 blocks per matrix
        int idx = (b & 63) * 256 + threadIdx.x;  // coalesced read
        float v = ms[mat][idx];
        int k = idx >> 7, n = idx & 127;
        unsigned short h = f2bf(v);
        size_t o = ((size_t)mat << 14) + (size_t)n * DD + k;
        whi[o] = h;
        wlo[o] = f2bf(v - bf2f(h));
    } else {
        int e = (bid - PRE_CVT_BLKS - PRE_W_BLKS) * 256 + threadIdx.x;
        if (e < NE) atomicAdd(&cnt[dst[e]], 1);
    }
}

// ---------------------------------------------------------------------------
// scan_k, 2 blocks:
//   block 0: 3-phase exclusive scan of cnt -> row_ptr/cursor (int4 loads)
//   block 1: per-graph node counts via 65 binary searches (batch sorted),
//            cntG[g] = lower_bound(g+1) - lower_bound(g).  No atomics.
// ---------------------------------------------------------------------------
__global__ __launch_bounds__(1024) void scan_k(const int* __restrict__ cnt,
                                               int* __restrict__ row_ptr,
                                               int* __restrict__ cursor,
                                               const int* __restrict__ batch,
                                               int* __restrict__ cntG)
{
    __shared__ int sm[1024];
    __shared__ int st[NG + 1];
    int t = threadIdx.x;

    if (blockIdx.x == 1) {                   // binary-search block
        if (t <= NG) {
            int lo = 0, hi = NN;
            while (lo < hi) {
                int mid = (lo + hi) >> 1;
                if (batch[mid] < t) lo = mid + 1; else hi = mid;
            }
            st[t] = lo;
        }
        __syncthreads();
        if (t < NG) cntG[t] = st[t + 1] - st[t];
        return;
    }

    int base = t * 40;                       // 1024*40 = 40960 >= NN, 16B-aligned
    int4 buf[10];
    if (base + 40 <= NN) {
#pragma unroll
        for (int i = 0; i < 10; ++i) buf[i] = ((const int4*)(cnt + base))[i];
    } else {
#pragma unroll
        for (int i = 0; i < 10; ++i) {
            int idx = base + i * 4;
            int4 v = make_int4(0, 0, 0, 0);
            if (idx + 0 < NN) v.x = cnt[idx + 0];
            if (idx + 1 < NN) v.y = cnt[idx + 1];
            if (idx + 2 < NN) v.z = cnt[idx + 2];
            if (idx + 3 < NN) v.w = cnt[idx + 3];
            buf[i] = v;
        }
    }
    int s = 0;
#pragma unroll
    for (int i = 0; i < 10; ++i) s += buf[i].x + buf[i].y + buf[i].z + buf[i].w;
    sm[t] = s;
    __syncthreads();
    for (int off = 1; off < 1024; off <<= 1) {
        int x = (t >= off) ? sm[t - off] : 0;
        __syncthreads();
        sm[t] += x;
        __syncthreads();
    }
    int run = sm[t] - s;                     // exclusive prefix
#pragma unroll
    for (int i = 0; i < 10; ++i) {
        int idx = base + i * 4;
        if (idx + 0 < NN) { row_ptr[idx + 0] = run; cursor[idx + 0] = run; run += buf[i].x; }
        if (idx + 1 < NN) { row_ptr[idx + 1] = run; cursor[idx + 1] = run; run += buf[i].y; }
        if (idx + 2 < NN) { row_ptr[idx + 2] = run; cursor[idx + 2] = run; run += buf[i].z; }
        if (idx + 3 < NN) { row_ptr[idx + 3] = run; cursor[idx + 3] = run; run += buf[i].w; }
    }
    if (t == 1023) row_ptr[NN] = run;        // == NE
}

// elist[pos] = (src, eid) for layer 0; srcA[pos] = src for layers 1-3.
__global__ __launch_bounds__(256) void fill_k(const int* __restrict__ src,
                                              const int* __restrict__ dst,
                                              int* __restrict__ cursor,
                                              int2* __restrict__ elist,
                                              int* __restrict__ srcA)
{
    int e = blockIdx.x * 256 + threadIdx.x;
    if (e < NE) {
        int d = dst[e];
        int s = src[e];
        int pos = atomicAdd(&cursor[d], 1);
        elist[pos] = make_int2(s, e);
        srcA[pos] = s;
    }
}

// ---------------------------------------------------------------------------
// Standalone gather (full occupancy; R6 showed fusing it to 2 blocks/CU
// loses ~50 us/layer).  agg[n] = h[n] + sum_e relu(h[src_e] + ea_e).
// L0=1: reads elist(src,eid) + ea fp32 (nt), converts, writes ea_bf[pos]
//   -> ea_bf is CSR-ORDERED (sequential per node).
// L0=0: reads srcA[pos] (4B) + ea_bf[pos] SEQUENTIALLY (nt); h random
//   (L3-served: hB = 10 MB).
// ---------------------------------------------------------------------------
template <int L0>
__global__ __launch_bounds__(256) void gather_bf(
    const unsigned short* __restrict__ hb,
    const float* __restrict__ ea, unsigned short* __restrict__ ea_bf,
    const int2* __restrict__ elist, const int* __restrict__ srcA,
    const int* __restrict__ row_ptr, float* __restrict__ agg)
{
    int grp = blockIdx.x * 8 + (threadIdx.x >> 5);   // node id
    int lane = threadIdx.x & 31;
    if (grp >= NN) return;
    int beg = row_ptr[grp], end = row_ptr[grp + 1];

    float4 a0 = make_float4(0.f, 0.f, 0.f, 0.f);
    float4 a1 = make_float4(0.f, 0.f, 0.f, 0.f);
    float4 a2 = make_float4(0.f, 0.f, 0.f, 0.f);
    float4 a3 = make_float4(0.f, 0.f, 0.f, 0.f);
    auto edge = [&](float4& acc, int pos) {
        us4 xv, bv;
        if (L0) {
            int2 pr = elist[pos];
            xv = *(const us4*)(hb + (size_t)pr.x * DD + lane * 4);
            vf4 ev = __builtin_nontemporal_load(
                (const vf4*)(ea + (size_t)pr.y * DD + lane * 4));
            bv = (us4){f2bf(ev.x), f2bf(ev.y), f2bf(ev.z), f2bf(ev.w)};
            *(us4*)(ea_bf + (size_t)pos * DD + lane * 4) = bv;   // CSR order
        } else {
            int s = srcA[pos];
            xv = *(const us4*)(hb + (size_t)s * DD + lane * 4);
            bv = __builtin_nontemporal_load(
                (const us4*)(ea_bf + (size_t)pos * DD + lane * 4));
        }
        acc.x += fmaxf(bf2f(xv.x) + bf2f(bv.x), 0.f);
        acc.y += fmaxf(bf2f(xv.y) + bf2f(bv.y), 0.f);
        acc.z += fmaxf(bf2f(xv.z) + bf2f(bv.z), 0.f);
        acc.w += fmaxf(bf2f(xv.w) + bf2f(bv.w), 0.f);
    };
    int pos = beg;
    for (; pos + 4 <= end; pos += 4) {
        edge(a0, pos); edge(a1, pos + 1); edge(a2, pos + 2); edge(a3, pos + 3);
    }
    for (; pos < end; ++pos) edge(a0, pos);

    us4 sv = *(const us4*)(hb + (size_t)grp * DD + lane * 4);
    float4 o;
    o.x = bf2f(sv.x) + (a0.x + a1.x) + (a2.x + a3.x);
    o.y = bf2f(sv.y) + (a0.y + a1.y) + (a2.y + a3.y);
    o.z = bf2f(sv.z) + (a0.z + a1.z) + (a2.z + a3.z);
    o.w = bf2f(sv.w) + (a0.w + a1.w) + (a2.w + a3.w);
    *(float4*)(agg + (size_t)grp * DD + lane * 4) = o;
}

// fp32 fallback gather (only if ws can't hold the bf16 edge cache)
__device__ inline void acc1f(float4& acc, const float* __restrict__ h,
                             const float* __restrict__ ea,
                             int s, int id, int lane)
{
    const float4 xv = *(const float4*)(h + (size_t)s * DD + lane * 4);
    vf4 ev = __builtin_nontemporal_load((const vf4*)(ea + (size_t)id * DD + lane * 4));
    acc.x += fmaxf(xv.x + ev.x, 0.f);
    acc.y += fmaxf(xv.y + ev.y, 0.f);
    acc.z += fmaxf(xv.z + ev.z, 0.f);
    acc.w += fmaxf(xv.w + ev.w, 0.f);
}

__global__ __launch_bounds__(256) void gather_f32(
    const float* __restrict__ h, const float* __restrict__ ea,
    const int* __restrict__ row_ptr, const int2* __restrict__ elist,
    float* __restrict__ agg)
{
    int grp = blockIdx.x * 8 + (threadIdx.x >> 5);
    int lane = threadIdx.x & 31;
    if (grp >= NN) return;
    int beg = row_ptr[grp], end = row_ptr[grp + 1];

    float4 a0 = make_float4(0.f, 0.f, 0.f, 0.f);
    float4 a1 = make_float4(0.f, 0.f, 0.f, 0.f);
    float4 a2 = make_float4(0.f, 0.f, 0.f, 0.f);
    float4 a3 = make_float4(0.f, 0.f, 0.f, 0.f);
    int e = beg;
    for (; e + 4 <= end; e += 4) {
        int2 p0 = elist[e];
        int2 p1 = elist[e + 1];
        int2 p2 = elist[e + 2];
        int2 p3 = elist[e + 3];
        acc1f(a0, h, ea, p0.x, p0.y, lane);
        acc1f(a1, h, ea, p1.x, p1.y, lane);
        acc1f(a2, h, ea, p2.x, p2.y, lane);
        acc1f(a3, h, ea, p3.x, p3.y, lane);
    }
    for (; e < end; ++e) {
        int2 p0 = elist[e];
        acc1f(a0, h, ea, p0.x, p0.y, lane);
    }
    const float4 sv = *(const float4*)(h + (size_t)grp * DD + lane * 4);
    float4 o;
    o.x = sv.x + (a0.x + a1.x) + (a2.x + a3.x);
    o.y = sv.y + (a0.y + a1.y) + (a2.y + a3.y);
    o.z = sv.z + (a0.z + a1.z) + (a2.z + a3.z);
    o.w = sv.w + (a0.w + a1.w) + (a2.w + a3.w);
    *(float4*)(agg + (size_t)grp * DD + lane * 4) = o;
}

// ---------------------------------------------------------------------------
// Slim fused 2-layer MLP (split-bf16 MFMA):  v = relu(relu(A@W1+b1)@W2+b2)
// CHANGE vs R8: NO B staging in LDS — W fragments are read directly from
// global.  Weights are 512 KB total -> fully L2-resident (hit ~34 TB/s);
// a wave's fragment load touches 16 rows x 64 B contiguous = L2-friendly.
// LDS 64->32 KB (A hi/lo only) and __launch_bounds__(256,4) -> 4 blocks/CU
// (was 2); barriers 7 -> 3.  Numerics bit-identical (same 3-MFMA split
// Ah*Wh + Ah*Wl + Al*Wh, same fp32 accum order: nf inner loop ks).
// MODE 0: fp32 C.  MODE 1: bf16 Cb.  MODE 2: pool epilogue (LDS run-reduce
// over sorted batch, ~2 atomics/col/block).
// XOR swizzle byte^=(row&7)<<4 on LDS A writes AND reads (G4).
// ---------------------------------------------------------------------------
template <int MODE>
__global__ __launch_bounds__(256, 4) void mlp_fused(
    const float* __restrict__ A,
    const unsigned short* __restrict__ W1h, const unsigned short* __restrict__ W1l,
    const float* __restrict__ b1v,
    const unsigned short* __restrict__ W2h, const unsigned short* __restrict__ W2l,
    const float* __restrict__ b2v,
    float* C, unsigned short* Cb,
    float* __restrict__ outp, const int* __restrict__ batch)
{
    __shared__ __align__(16) char lds[32 * 1024];
    __shared__ int sbatch[64];
    char* lAh = lds;                 // 16 KB  [64 r][128 k] bf16, swizzled
    char* lAl = lds + 16 * 1024;     // 16 KB

    const int tid = threadIdx.x;
    const int m0 = blockIdx.x * 64;

    // ---- stage A: fp32 -> split bf16, 64 rows x 128 (32 floats/thread)
    {
        const int row = tid >> 2;
        const int c0 = (tid & 3) * 32;
        const float* srcp = A + (size_t)(m0 + row) * DD + c0;
        const int base = row * 256 + c0 * 2;
        const int sw = (row & 7) << 4;
#pragma unroll
        for (int i = 0; i < 4; ++i) {
            float4 v0 = *(const float4*)(srcp + i * 8);
            float4 v1 = *(const float4*)(srcp + i * 8 + 4);
            float f[8] = {v0.x, v0.y, v0.z, v0.w, v1.x, v1.y, v1.z, v1.w};
            us8 hv, lv;
#pragma unroll
            for (int j = 0; j < 8; ++j) {
                unsigned short hb = f2bf(f[j]);
                hv[j] = hb;
                lv[j] = f2bf(f[j] - bf2f(hb));
            }
            const int off = (base + i * 16) ^ sw;
            *(us8*)(lAh + off) = hv;
            *(us8*)(lAl + off) = lv;
        }
    }
    __syncthreads();

    // ---- fragment geometry (m89-verified 16x16x32 layouts)
    const int lane64 = tid & 63;
    const int wid = tid >> 6;
    const int lr = lane64 & 15;
    const int kg = lane64 >> 4;
    const int swr = (lr & 7) << 4;

    bf16x8 ah[4], al[4];
    auto loadA = [&]() {
#pragma unroll
        for (int ks = 0; ks < 4; ++ks) {
            const int off = ((wid * 16 + lr) * 256 + ks * 64 + kg * 16) ^ swr;
            ah[ks] = *(const bf16x8*)(lAh + off);
            al[ks] = *(const bf16x8*)(lAl + off);
        }
    };
    f32x4 acc[8];
    // B fragment straight from global: col = nf*16+lr, k = ks*32+kg*8
    auto mfma_all = [&](const unsigned short* __restrict__ Wh_,
                        const unsigned short* __restrict__ Wl_) {
#pragma unroll
        for (int nf = 0; nf < 8; ++nf) {
            const size_t cbase = (size_t)(nf * 16 + lr) * DD + kg * 8;
#pragma unroll
            for (int ks = 0; ks < 4; ++ks) {
                bf16x8 bh = *(const bf16x8*)(Wh_ + cbase + ks * 32);
                bf16x8 bl = *(const bf16x8*)(Wl_ + cbase + ks * 32);
                acc[nf] = __builtin_amdgcn_mfma_f32_16x16x32_bf16(ah[ks], bh, acc[nf], 0, 0, 0);
                acc[nf] = __builtin_amdgcn_mfma_f32_16x16x32_bf16(ah[ks], bl, acc[nf], 0, 0, 0);
                acc[nf] = __builtin_amdgcn_mfma_f32_16x16x32_bf16(al[ks], bh, acc[nf], 0, 0, 0);
            }
        }
    };

    // phase 1: u = relu(A @ W1 + b1)
    loadA();
#pragma unroll
    for (int nf = 0; nf < 8; ++nf) acc[nf] = (f32x4){0.f, 0.f, 0.f, 0.f};
    mfma_all(W1h, W1l);
    __syncthreads();                 // all loadA reads done before u-writeback

    // u -> split bf16 back into lA (swizzled)
#pragma unroll
    for (int nf = 0; nf < 8; ++nf) {
        const int col = nf * 16 + lr;
        const float b = b1v[col];
#pragma unroll
        for (int r = 0; r < 4; ++r) {
            float u = fmaxf(acc[nf][r] + b, 0.0f);
            const int lrow = wid * 16 + kg * 4 + r;
            const int off = (lrow * 256 + col * 2) ^ ((lrow & 7) << 4);
            unsigned short hb = f2bf(u);
            *(unsigned short*)(lAh + off) = hb;
            *(unsigned short*)(lAl + off) = f2bf(u - bf2f(hb));
        }
    }
    __syncthreads();

    // phase 2: v = relu(u @ W2 + b2)
    loadA();
#pragma unroll
    for (int nf = 0; nf < 8; ++nf) acc[nf] = (f32x4){0.f, 0.f, 0.f, 0.f};
    mfma_all(W2h, W2l);

    // ---- epilogue
    if (MODE == 0) {
#pragma unroll
        for (int nf = 0; nf < 8; ++nf) {
            const int col = nf * 16 + lr;
            const float b = b2v[col];
            const size_t rbase = (size_t)(m0 + wid * 16 + kg * 4) * DD + col;
#pragma unroll
            for (int r = 0; r < 4; ++r)
                C[rbase + (size_t)r * DD] = fmaxf(acc[nf][r] + b, 0.0f);
        }
    } else if (MODE == 1) {
#pragma unroll
        for (int nf = 0; nf < 8; ++nf) {
            const int col = nf * 16 + lr;
            const float b = b2v[col];
            const size_t rbase = (size_t)(m0 + wid * 16 + kg * 4) * DD + col;
#pragma unroll
            for (int r = 0; r < 4; ++r)
                Cb[rbase + (size_t)r * DD] = f2bf(fmaxf(acc[nf][r] + b, 0.0f));
        }
    } else {
        // pool epilogue: stage v fp32 over the lA region, run-reduce per
        // column over sorted batch.  Barrier ensures all loadA reads done.
        float* pstage = (float*)lds;           // 32 KB = 64*128*4
        if (tid < 64) sbatch[tid] = batch[m0 + tid];
        __syncthreads();
#pragma unroll
        for (int nf = 0; nf < 8; ++nf) {
            const int col = nf * 16 + lr;
            const float b = b2v[col];
            const int row = wid * 16 + kg * 4;
#pragma unroll
            for (int r = 0; r < 4; ++r)
                pstage[(row + r) * DD + col] = fmaxf(acc[nf][r] + b, 0.0f);
        }
        __syncthreads();
        const int col = tid & 127;
        const int row0 = (tid >> 7) * 32;
        float run = 0.f;
        int gprev = sbatch[row0];
        for (int r = row0; r < row0 + 32; ++r) {
            int gg = sbatch[r];
            if (gg != gprev) {
                unsafeAtomicAdd(outp + (size_t)gprev * DD + col, run);
                run = 0.f;
                gprev = gg;
            }
            run += pstage[r * DD + col];
        }
        unsafeAtomicAdd(outp + (size_t)gprev * DD + col, run);
    }
}

// ---------------------------------------------------------------------------
// Fallback pool (counts come from scan_k's bsearch block — no atomics here)
// ---------------------------------------------------------------------------
__device__ inline void pool_flush(float* __restrict__ out, int g, int lane,
                                  const float4& acc)
{
    float* o = out + (size_t)g * DD + lane * 4;
    unsafeAtomicAdd(o + 0, acc.x);
    unsafeAtomicAdd(o + 1, acc.y);
    unsafeAtomicAdd(o + 2, acc.z);
    unsafeAtomicAdd(o + 3, acc.w);
}

__global__ __launch_bounds__(256) void pool_k(
    const float* __restrict__ h, const int* __restrict__ batch,
    float* __restrict__ out)
{
    int tid = blockIdx.x * 256 + threadIdx.x;
    int grp = tid >> 5;
    int lane = tid & 31;
    int n0 = grp * 16;
    if (n0 >= NN) return;
    int nend = min(n0 + 16, NN);

    float4 acc = make_float4(0.f, 0.f, 0.f, 0.f);
    int gprev = batch[n0];
    for (int n = n0; n < nend; ++n) {
        int g = batch[n];
        if (g != gprev) {
            pool_flush(out, gprev, lane, acc);
            acc = make_float4(0.f, 0.f, 0.f, 0.f);
            gprev = g;
        }
        float4 v = *(const float4*)(h + (size_t)n * DD + lane * 4);
        acc.x += v.x; acc.y += v.y; acc.z += v.z; acc.w += v.w;
    }
    pool_flush(out, gprev, lane, acc);
}

__global__ __launch_bounds__(256) void pool_div_k(float* __restrict__ out,
                                                  const int* __restrict__ cnt)
{
    int tid = blockIdx.x * 256 + threadIdx.x;
    if (tid >= NG * DD) return;
    int g = tid / DD;
    float c = fmaxf((float)cnt[g], 1.0f);
    out[tid] = out[tid] / c;
}

// ---------------------------------------------------------------------------
extern "C" void kernel_launch(void* const* d_in, const int* in_sizes, int n_in,
                              void* d_out, int out_size, void* d_ws, size_t ws_size,
                              hipStream_t stream)
{
    const float* x     = (const float*)d_in[0];
    const float* ea    = (const float*)d_in[1];
    const int*   ei    = (const int*)d_in[2];
    const int*   batch = (const int*)d_in[3];
    const float* w1[4], * b1[4], * w2[4], * b2[4];
    for (int l = 0; l < 4; ++l) {
        w1[l] = (const float*)d_in[4 + 4 * l];
        b1[l] = (const float*)d_in[5 + 4 * l];
        w2[l] = (const float*)d_in[6 + 4 * l];
        b2[l] = (const float*)d_in[7 + 4 * l];
    }

    const int* srcp = ei;            // edge_index[0]
    const int* dstp = ei + NE;       // edge_index[1]

    char* ws = (char*)d_ws;
    const size_t hbytes = (size_t)NN * DD * sizeof(float);   // 20.48 MB
    float* agg = (float*)ws;
    float* hA  = (float*)(ws + hbytes);                      // fallback only
    char*  p   = ws + 2 * hbytes;
    int*  cnt_node = (int*)p;           p += ((NN * 4 + 255) & ~255);
    int*  row_ptr  = (int*)p;           p += (((NN + 1) * 4 + 255) & ~255);
    int*  cursor   = (int*)p;           p += ((NN * 4 + 255) & ~255);
    int2* elist    = (int2*)p;          p += (((size_t)NE * 8 + 255) & ~255);
    int*  srcA     = (int*)p;           p += (((size_t)NE * 4 + 255) & ~255);
    int*  cntG     = (int*)p;           p += 256;
    unsigned short* wt_hi = (unsigned short*)p;  p += (size_t)8 * 16384 * 2;  // 256 KB
    unsigned short* wt_lo = (unsigned short*)p;  p += (size_t)8 * 16384 * 2;  // 256 KB
    unsigned short* hB = (unsigned short*)p;     p += (size_t)NN * DD * 2;    // 10.24 MB
    unsigned short* ea_bf = (unsigned short*)p;
    const size_t need_bf = (size_t)(p - ws) + (size_t)NE * DD * 2;
    const bool use_bf = (ws_size >= need_bf);   // ws_size is call-invariant

    const int eblocks     = (NE + 255) / 256;   // 2500
    const int gblocks     = (NN + 7) / 8;       // 5000
    const int gemm_blocks = NN / 64;            // 625
    const int pool_blocks = ((NN / 16) * 32 + 255) / 256;

    // ---- one-time: memsets + preamble + scan(+bsearch) + fill
    hipMemsetAsync(cnt_node, 0, NN * sizeof(int), stream);
    hipMemsetAsync(d_out, 0, (size_t)NG * DD * sizeof(float), stream);
    if (use_bf)
        preamble_k<1><<<PRE_BLOCKS, 256, 0, stream>>>(
            x, hB, w1[0], w2[0], w1[1], w2[1], w1[2], w2[2], w1[3], w2[3],
            wt_hi, wt_lo, dstp, cnt_node);
    else
        preamble_k<0><<<PRE_BLOCKS, 256, 0, stream>>>(
            x, nullptr, w1[0], w2[0], w1[1], w2[1], w1[2], w2[2], w1[3], w2[3],
            wt_hi, wt_lo, dstp, cnt_node);
    scan_k<<<2, 1024, 0, stream>>>(cnt_node, row_ptr, cursor, batch, cntG);
    fill_k<<<eblocks, 256, 0, stream>>>(srcp, dstp, cursor, elist, srcA);

    if (use_bf) {
        const unsigned short* wh[8];
        const unsigned short* wl[8];
        for (int m = 0; m < 8; ++m) {
            wh[m] = wt_hi + ((size_t)m << 14);
            wl[m] = wt_lo + ((size_t)m << 14);
        }
        for (int l = 0; l < 4; ++l) {
            if (l == 0)
                gather_bf<1><<<gblocks, 256, 0, stream>>>(
                    hB, ea, ea_bf, elist, nullptr, row_ptr, agg);
            else
                gather_bf<0><<<gblocks, 256, 0, stream>>>(
                    hB, nullptr, ea_bf, nullptr, srcA, row_ptr, agg);
            if (l < 3)
                mlp_fused<1><<<gemm_blocks, 256, 0, stream>>>(
                    agg, wh[2 * l], wl[2 * l], b1[l],
                    wh[2 * l + 1], wl[2 * l + 1], b2[l],
                    nullptr, hB, nullptr, nullptr);
            else
                mlp_fused<2><<<gemm_blocks, 256, 0, stream>>>(
                    agg, wh[2 * l], wl[2 * l], b1[l],
                    wh[2 * l + 1], wl[2 * l + 1], b2[l],
                    nullptr, nullptr, (float*)d_out, batch);
        }
    } else {
        const float* hcur = x;
        for (int l = 0; l < 4; ++l) {
            gather_f32<<<gblocks, 256, 0, stream>>>(hcur, ea, row_ptr, elist, agg);
            const unsigned short* h1  = wt_hi + ((size_t)(2 * l) << 14);
            const unsigned short* lo1 = wt_lo + ((size_t)(2 * l) << 14);
            const unsigned short* h2  = wt_hi + ((size_t)(2 * l + 1) << 14);
            const unsigned short* lo2 = wt_lo + ((size_t)(2 * l + 1) << 14);
            mlp_fused<0><<<gemm_blocks, 256, 0, stream>>>(
                agg, h1, lo1, b1[l], h2, lo2, b2[l], hA, nullptr, nullptr, nullptr);
            hcur = hA;
        }
        pool_k<<<pool_blocks, 256, 0, stream>>>(hA, batch, (float*)d_out);
    }

    pool_div_k<<<(NG * DD + 255) / 256, 256, 0, stream>>>((float*)d_out, cntG);
}

// Round 10
// 851.025 us; speedup vs baseline: 1.1249x; 1.1249x over previous
//
#include <hip/hip_runtime.h>

#define NN 40000      // nodes
#define NE 640000     // edges
#define DD 128        // feature dim
#define NG 64         // graphs

typedef float vf4 __attribute__((ext_vector_type(4)));
typedef unsigned short us4 __attribute__((ext_vector_type(4)));
typedef unsigned short us8 __attribute__((ext_vector_type(8)));
typedef short bf16x8 __attribute__((ext_vector_type(8)));
typedef float f32x4 __attribute__((ext_vector_type(4)));

__device__ inline unsigned short f2bf(float f) {        // round-nearest-even
    unsigned int u = __float_as_uint(f);
    return (unsigned short)((u + 0x7fffu + ((u >> 16) & 1u)) >> 16);
}
__device__ inline float bf2f(unsigned short s) {
    return __uint_as_float((unsigned int)s << 16);
}

// ---------------------------------------------------------------------------
// Fused preamble: x->bf16 | weight split | dst histogram.
// ---------------------------------------------------------------------------
#define PRE_CVT_BLKS  2500
#define PRE_W_BLKS    512
#define PRE_H_BLKS    2500
#define PRE_BLOCKS    (PRE_CVT_BLKS + PRE_W_BLKS + PRE_H_BLKS)

template <int USE_BF>
__global__ __launch_bounds__(256) void preamble_k(
    const float* __restrict__ x, unsigned short* __restrict__ hB,
    const float* __restrict__ m0, const float* __restrict__ m1,
    const float* __restrict__ m2, const float* __restrict__ m3,
    const float* __restrict__ m4, const float* __restrict__ m5,
    const float* __restrict__ m6, const float* __restrict__ m7,
    unsigned short* __restrict__ whi, unsigned short* __restrict__ wlo,
    const int* __restrict__ dst, int* __restrict__ cnt)
{
    const int bid = blockIdx.x;
    if (bid < PRE_CVT_BLKS) {
        if (!USE_BF) return;
        size_t i = ((size_t)bid * 256 + threadIdx.x) * 8;   // exact cover
        vf4 a = __builtin_nontemporal_load((const vf4*)(x + i));
        vf4 b = __builtin_nontemporal_load((const vf4*)(x + i + 4));
        us4 o0 = {f2bf(a.x), f2bf(a.y), f2bf(a.z), f2bf(a.w)};
        us4 o1 = {f2bf(b.x), f2bf(b.y), f2bf(b.z), f2bf(b.w)};
        *(us4*)(hB + i) = o0;
        *(us4*)(hB + i + 4) = o1;
    } else if (bid < PRE_CVT_BLKS + PRE_W_BLKS) {
        const float* ms[8] = {m0, m1, m2, m3, m4, m5, m6, m7};
        int b = bid - PRE_CVT_BLKS;
        int mat = b >> 6;                        // 64 blocks per matrix
        int idx = (b & 63) * 256 + threadIdx.x;  // coalesced read
        float v = ms[mat][idx];
        int k = idx >> 7, n = idx & 127;
        unsigned short h = f2bf(v);
        size_t o = ((size_t)mat << 14) + (size_t)n * DD + k;
        whi[o] = h;
        wlo[o] = f2bf(v - bf2f(h));
    } else {
        int e = (bid - PRE_CVT_BLKS - PRE_W_BLKS) * 256 + threadIdx.x;
        if (e < NE) atomicAdd(&cnt[dst[e]], 1);
    }
}

// ---------------------------------------------------------------------------
// scan_k, 2 blocks:
//   block 0: 3-phase exclusive scan of cnt -> row_ptr/cursor (int4 loads)
//   block 1: per-graph node counts via 65 binary searches (batch sorted).
// ---------------------------------------------------------------------------
__global__ __launch_bounds__(1024) void scan_k(const int* __restrict__ cnt,
                                               int* __restrict__ row_ptr,
                                               int* __restrict__ cursor,
                                               const int* __restrict__ batch,
                                               int* __restrict__ cntG)
{
    __shared__ int sm[1024];
    __shared__ int st[NG + 1];
    int t = threadIdx.x;

    if (blockIdx.x == 1) {                   // binary-search block
        if (t <= NG) {
            int lo = 0, hi = NN;
            while (lo < hi) {
                int mid = (lo + hi) >> 1;
                if (batch[mid] < t) lo = mid + 1; else hi = mid;
            }
            st[t] = lo;
        }
        __syncthreads();
        if (t < NG) cntG[t] = st[t + 1] - st[t];
        return;
    }

    int base = t * 40;                       // 1024*40 = 40960 >= NN, 16B-aligned
    int4 buf[10];
    if (base + 40 <= NN) {
#pragma unroll
        for (int i = 0; i < 10; ++i) buf[i] = ((const int4*)(cnt + base))[i];
    } else {
#pragma unroll
        for (int i = 0; i < 10; ++i) {
            int idx = base + i * 4;
            int4 v = make_int4(0, 0, 0, 0);
            if (idx + 0 < NN) v.x = cnt[idx + 0];
            if (idx + 1 < NN) v.y = cnt[idx + 1];
            if (idx + 2 < NN) v.z = cnt[idx + 2];
            if (idx + 3 < NN) v.w = cnt[idx + 3];
            buf[i] = v;
        }
    }
    int s = 0;
#pragma unroll
    for (int i = 0; i < 10; ++i) s += buf[i].x + buf[i].y + buf[i].z + buf[i].w;
    sm[t] = s;
    __syncthreads();
    for (int off = 1; off < 1024; off <<= 1) {
        int x = (t >= off) ? sm[t - off] : 0;
        __syncthreads();
        sm[t] += x;
        __syncthreads();
    }
    int run = sm[t] - s;                     // exclusive prefix
#pragma unroll
    for (int i = 0; i < 10; ++i) {
        int idx = base + i * 4;
        if (idx + 0 < NN) { row_ptr[idx + 0] = run; cursor[idx + 0] = run; run += buf[i].x; }
        if (idx + 1 < NN) { row_ptr[idx + 1] = run; cursor[idx + 1] = run; run += buf[i].y; }
        if (idx + 2 < NN) { row_ptr[idx + 2] = run; cursor[idx + 2] = run; run += buf[i].z; }
        if (idx + 3 < NN) { row_ptr[idx + 3] = run; cursor[idx + 3] = run; run += buf[i].w; }
    }
    if (t == 1023) row_ptr[NN] = run;        // == NE
}

// elist[pos] = (src, eid) for layer 0; srcA[pos] = src for layers 1-3.
__global__ __launch_bounds__(256) void fill_k(const int* __restrict__ src,
                                              const int* __restrict__ dst,
                                              int* __restrict__ cursor,
                                              int2* __restrict__ elist,
                                              int* __restrict__ srcA)
{
    int e = blockIdx.x * 256 + threadIdx.x;
    if (e < NE) {
        int d = dst[e];
        int s = src[e];
        int pos = atomicAdd(&cursor[d], 1);
        elist[pos] = make_int2(s, e);
        srcA[pos] = s;
    }
}

// ---------------------------------------------------------------------------
// Standalone gather (full occupancy).  agg[n] = h[n] + sum_e relu(h[src]+ea).
// L0=1: reads elist(src,eid) + ea fp32 (nt), converts, writes ea_bf[pos]
//   -> ea_bf is CSR-ORDERED (sequential per node).
// L0=0: reads srcA[pos] (4B) + ea_bf[pos] SEQUENTIALLY (nt); h random.
// ---------------------------------------------------------------------------
template <int L0>
__global__ __launch_bounds__(256) void gather_bf(
    const unsigned short* __restrict__ hb,
    const float* __restrict__ ea, unsigned short* __restrict__ ea_bf,
    const int2* __restrict__ elist, const int* __restrict__ srcA,
    const int* __restrict__ row_ptr, float* __restrict__ agg)
{
    int grp = blockIdx.x * 8 + (threadIdx.x >> 5);   // node id
    int lane = threadIdx.x & 31;
    if (grp >= NN) return;
    int beg = row_ptr[grp], end = row_ptr[grp + 1];

    float4 a0 = make_float4(0.f, 0.f, 0.f, 0.f);
    float4 a1 = make_float4(0.f, 0.f, 0.f, 0.f);
    float4 a2 = make_float4(0.f, 0.f, 0.f, 0.f);
    float4 a3 = make_float4(0.f, 0.f, 0.f, 0.f);
    auto edge = [&](float4& acc, int pos) {
        us4 xv, bv;
        if (L0) {
            int2 pr = elist[pos];
            xv = *(const us4*)(hb + (size_t)pr.x * DD + lane * 4);
            vf4 ev = __builtin_nontemporal_load(
                (const vf4*)(ea + (size_t)pr.y * DD + lane * 4));
            bv = (us4){f2bf(ev.x), f2bf(ev.y), f2bf(ev.z), f2bf(ev.w)};
            *(us4*)(ea_bf + (size_t)pos * DD + lane * 4) = bv;   // CSR order
        } else {
            int s = srcA[pos];
            xv = *(const us4*)(hb + (size_t)s * DD + lane * 4);
            bv = __builtin_nontemporal_load(
                (const us4*)(ea_bf + (size_t)pos * DD + lane * 4));
        }
        acc.x += fmaxf(bf2f(xv.x) + bf2f(bv.x), 0.f);
        acc.y += fmaxf(bf2f(xv.y) + bf2f(bv.y), 0.f);
        acc.z += fmaxf(bf2f(xv.z) + bf2f(bv.z), 0.f);
        acc.w += fmaxf(bf2f(xv.w) + bf2f(bv.w), 0.f);
    };
    int pos = beg;
    for (; pos + 4 <= end; pos += 4) {
        edge(a0, pos); edge(a1, pos + 1); edge(a2, pos + 2); edge(a3, pos + 3);
    }
    for (; pos < end; ++pos) edge(a0, pos);

    us4 sv = *(const us4*)(hb + (size_t)grp * DD + lane * 4);
    float4 o;
    o.x = bf2f(sv.x) + (a0.x + a1.x) + (a2.x + a3.x);
    o.y = bf2f(sv.y) + (a0.y + a1.y) + (a2.y + a3.y);
    o.z = bf2f(sv.z) + (a0.z + a1.z) + (a2.z + a3.z);
    o.w = bf2f(sv.w) + (a0.w + a1.w) + (a2.w + a3.w);
    *(float4*)(agg + (size_t)grp * DD + lane * 4) = o;
}

// fp32 fallback gather (only if ws can't hold the bf16 edge cache)
__device__ inline void acc1f(float4& acc, const float* __restrict__ h,
                             const float* __restrict__ ea,
                             int s, int id, int lane)
{
    const float4 xv = *(const float4*)(h + (size_t)s * DD + lane * 4);
    vf4 ev = __builtin_nontemporal_load((const vf4*)(ea + (size_t)id * DD + lane * 4));
    acc.x += fmaxf(xv.x + ev.x, 0.f);
    acc.y += fmaxf(xv.y + ev.y, 0.f);
    acc.z += fmaxf(xv.z + ev.z, 0.f);
    acc.w += fmaxf(xv.w + ev.w, 0.f);
}

__global__ __launch_bounds__(256) void gather_f32(
    const float* __restrict__ h, const float* __restrict__ ea,
    const int* __restrict__ row_ptr, const int2* __restrict__ elist,
    float* __restrict__ agg)
{
    int grp = blockIdx.x * 8 + (threadIdx.x >> 5);
    int lane = threadIdx.x & 31;
    if (grp >= NN) return;
    int beg = row_ptr[grp], end = row_ptr[grp + 1];

    float4 a0 = make_float4(0.f, 0.f, 0.f, 0.f);
    float4 a1 = make_float4(0.f, 0.f, 0.f, 0.f);
    float4 a2 = make_float4(0.f, 0.f, 0.f, 0.f);
    float4 a3 = make_float4(0.f, 0.f, 0.f, 0.f);
    int e = beg;
    for (; e + 4 <= end; e += 4) {
        int2 p0 = elist[e];
        int2 p1 = elist[e + 1];
        int2 p2 = elist[e + 2];
        int2 p3 = elist[e + 3];
        acc1f(a0, h, ea, p0.x, p0.y, lane);
        acc1f(a1, h, ea, p1.x, p1.y, lane);
        acc1f(a2, h, ea, p2.x, p2.y, lane);
        acc1f(a3, h, ea, p3.x, p3.y, lane);
    }
    for (; e < end; ++e) {
        int2 p0 = elist[e];
        acc1f(a0, h, ea, p0.x, p0.y, lane);
    }
    const float4 sv = *(const float4*)(h + (size_t)grp * DD + lane * 4);
    float4 o;
    o.x = sv.x + (a0.x + a1.x) + (a2.x + a3.x);
    o.y = sv.y + (a0.y + a1.y) + (a2.y + a3.y);
    o.z = sv.z + (a0.z + a1.z) + (a2.z + a3.z);
    o.w = sv.w + (a0.w + a1.w) + (a2.w + a3.w);
    *(float4*)(agg + (size_t)grp * DD + lane * 4) = o;
}

// ---------------------------------------------------------------------------
// Fused 2-layer MLP (split-bf16 MFMA) — R8's measured-best configuration:
// B staged in LDS in two 64-col halves (decouples MFMA from memory latency;
// R9's W-from-global variant lost 98 µs to per-wave L2 reads + latency
// serialization).  64 KB LDS -> 2 blocks/CU, u on-chip.
// MODE 0: fp32 C.  MODE 1: bf16 Cb.  MODE 2: pool epilogue.
// XOR swizzle byte^=(row&7)<<4 on all LDS A/B writes AND reads (G4).
// ---------------------------------------------------------------------------
template <int MODE>
__global__ __launch_bounds__(256, 2) void mlp_fused(
    const float* __restrict__ A,
    const unsigned short* __restrict__ W1h, const unsigned short* __restrict__ W1l,
    const float* __restrict__ b1v,
    const unsigned short* __restrict__ W2h, const unsigned short* __restrict__ W2l,
    const float* __restrict__ b2v,
    float* C, unsigned short* Cb,
    float* __restrict__ outp, const int* __restrict__ batch)
{
    __shared__ __align__(16) char lds[64 * 1024];
    __shared__ int sbatch[64];
    char* lAh = lds;                 // 16 KB  [64 r][128 k] bf16, swizzled
    char* lAl = lds + 16 * 1024;     // 16 KB
    char* lBh = lds + 32 * 1024;     // 16 KB  [64 c][128 k] bf16 (half of N)
    char* lBl = lds + 48 * 1024;     // 16 KB

    const int tid = threadIdx.x;
    const int m0 = blockIdx.x * 64;

    // W staging geometry: 64 cols/half, 4 threads per col, 32 k each
    const int wc  = tid >> 2;
    const int wk0 = (tid & 3) * 32;
    const int wbase = wc * 256 + wk0 * 2;
    const int wsw = (wc & 7) << 4;
    auto stageW = [&](const unsigned short* Wh_, const unsigned short* Wl_,
                      int col0) {
        const unsigned short* sh = Wh_ + (size_t)(col0 + wc) * DD + wk0;
        const unsigned short* sl = Wl_ + (size_t)(col0 + wc) * DD + wk0;
#pragma unroll
        for (int i = 0; i < 4; ++i) {
            const int off = (wbase + i * 16) ^ wsw;
            *(us8*)(lBh + off) = *(const us8*)(sh + i * 8);
            *(us8*)(lBl + off) = *(const us8*)(sl + i * 8);
        }
    };

    // ---- stage A: fp32 -> split bf16, 64 rows x 128 (32 floats/thread)
    {
        const int row = tid >> 2;
        const int c0 = (tid & 3) * 32;
        const float* srcp = A + (size_t)(m0 + row) * DD + c0;
        const int base = row * 256 + c0 * 2;
        const int sw = (row & 7) << 4;
#pragma unroll
        for (int i = 0; i < 4; ++i) {
            float4 v0 = *(const float4*)(srcp + i * 8);
            float4 v1 = *(const float4*)(srcp + i * 8 + 4);
            float f[8] = {v0.x, v0.y, v0.z, v0.w, v1.x, v1.y, v1.z, v1.w};
            us8 hv, lv;
#pragma unroll
            for (int j = 0; j < 8; ++j) {
                unsigned short hb = f2bf(f[j]);
                hv[j] = hb;
                lv[j] = f2bf(f[j] - bf2f(hb));
            }
            const int off = (base + i * 16) ^ sw;
            *(us8*)(lAh + off) = hv;
            *(us8*)(lAl + off) = lv;
        }
    }
    stageW(W1h, W1l, 0);
    __syncthreads();

    // ---- fragment geometry (m89-verified 16x16x32 layouts)
    const int lane64 = tid & 63;
    const int wid = tid >> 6;
    const int lr = lane64 & 15;
    const int kg = lane64 >> 4;
    const int swr = (lr & 7) << 4;

    bf16x8 ah[4], al[4];
    auto loadA = [&]() {
#pragma unroll
        for (int ks = 0; ks < 4; ++ks) {
            const int off = ((wid * 16 + lr) * 256 + ks * 64 + kg * 16) ^ swr;
            ah[ks] = *(const bf16x8*)(lAh + off);
            al[ks] = *(const bf16x8*)(lAl + off);
        }
    };
    f32x4 acc[8];
    auto mfma_half = [&](int ab) {
#pragma unroll
        for (int nfl = 0; nfl < 4; ++nfl) {
#pragma unroll
            for (int ks = 0; ks < 4; ++ks) {
                const int off = ((nfl * 16 + lr) * 256 + ks * 64 + kg * 16) ^ swr;
                bf16x8 bh = *(const bf16x8*)(lBh + off);
                bf16x8 bl = *(const bf16x8*)(lBl + off);
                acc[ab + nfl] = __builtin_amdgcn_mfma_f32_16x16x32_bf16(ah[ks], bh, acc[ab + nfl], 0, 0, 0);
                acc[ab + nfl] = __builtin_amdgcn_mfma_f32_16x16x32_bf16(ah[ks], bl, acc[ab + nfl], 0, 0, 0);
                acc[ab + nfl] = __builtin_amdgcn_mfma_f32_16x16x32_bf16(al[ks], bh, acc[ab + nfl], 0, 0, 0);
            }
        }
    };

    // phase 1: u = relu(A @ W1 + b1)
    loadA();
#pragma unroll
    for (int nf = 0; nf < 8; ++nf) acc[nf] = (f32x4){0.f, 0.f, 0.f, 0.f};
    mfma_half(0);
    __syncthreads();
    stageW(W1h, W1l, 64);
    __syncthreads();
    mfma_half(4);
    __syncthreads();

    // u -> split bf16 back into lA (swizzled); stage W2 half 0
#pragma unroll
    for (int nf = 0; nf < 8; ++nf) {
        const int col = nf * 16 + lr;
        const float b = b1v[col];
#pragma unroll
        for (int r = 0; r < 4; ++r) {
            float u = fmaxf(acc[nf][r] + b, 0.0f);
            const int lrow = wid * 16 + kg * 4 + r;
            const int off = (lrow * 256 + col * 2) ^ ((lrow & 7) << 4);
            unsigned short hb = f2bf(u);
            *(unsigned short*)(lAh + off) = hb;
            *(unsigned short*)(lAl + off) = f2bf(u - bf2f(hb));
        }
    }
    stageW(W2h, W2l, 0);
    __syncthreads();

    // phase 2: v = relu(u @ W2 + b2)
    loadA();
#pragma unroll
    for (int nf = 0; nf < 8; ++nf) acc[nf] = (f32x4){0.f, 0.f, 0.f, 0.f};
    mfma_half(0);
    __syncthreads();
    stageW(W2h, W2l, 64);
    __syncthreads();
    mfma_half(4);

    // ---- epilogue
    if (MODE == 0) {
#pragma unroll
        for (int nf = 0; nf < 8; ++nf) {
            const int col = nf * 16 + lr;
            const float b = b2v[col];
            const size_t rbase = (size_t)(m0 + wid * 16 + kg * 4) * DD + col;
#pragma unroll
            for (int r = 0; r < 4; ++r)
                C[rbase + (size_t)r * DD] = fmaxf(acc[nf][r] + b, 0.0f);
        }
    } else if (MODE == 1) {
#pragma unroll
        for (int nf = 0; nf < 8; ++nf) {
            const int col = nf * 16 + lr;
            const float b = b2v[col];
            const size_t rbase = (size_t)(m0 + wid * 16 + kg * 4) * DD + col;
#pragma unroll
            for (int r = 0; r < 4; ++r)
                Cb[rbase + (size_t)r * DD] = f2bf(fmaxf(acc[nf][r] + b, 0.0f));
        }
    } else {
        // pool epilogue: stage v fp32 in lA region (all lA reads are >= 2
        // barriers old), run-reduce per column over sorted batch.
        float* pstage = (float*)lds;           // 32 KB = 64*128*4
        if (tid < 64) sbatch[tid] = batch[m0 + tid];
        __syncthreads();                       // drain mfma_half(4) lB reads
#pragma unroll
        for (int nf = 0; nf < 8; ++nf) {
            const int col = nf * 16 + lr;
            const float b = b2v[col];
            const int row = wid * 16 + kg * 4;
#pragma unroll
            for (int r = 0; r < 4; ++r)
                pstage[(row + r) * DD + col] = fmaxf(acc[nf][r] + b, 0.0f);
        }
        __syncthreads();
        const int col = tid & 127;
        const int row0 = (tid >> 7) * 32;
        float run = 0.f;
        int gprev = sbatch[row0];
        for (int r = row0; r < row0 + 32; ++r) {
            int gg = sbatch[r];
            if (gg != gprev) {
                unsafeAtomicAdd(outp + (size_t)gprev * DD + col, run);
                run = 0.f;
                gprev = gg;
            }
            run += pstage[r * DD + col];
        }
        unsafeAtomicAdd(outp + (size_t)gprev * DD + col, run);
    }
}

// ---------------------------------------------------------------------------
// Fallback pool (counts come from scan_k's bsearch block — no atomics here)
// ---------------------------------------------------------------------------
__device__ inline void pool_flush(float* __restrict__ out, int g, int lane,
                                  const float4& acc)
{
    float* o = out + (size_t)g * DD + lane * 4;
    unsafeAtomicAdd(o + 0, acc.x);
    unsafeAtomicAdd(o + 1, acc.y);
    unsafeAtomicAdd(o + 2, acc.z);
    unsafeAtomicAdd(o + 3, acc.w);
}

__global__ __launch_bounds__(256) void pool_k(
    const float* __restrict__ h, const int* __restrict__ batch,
    float* __restrict__ out)
{
    int tid = blockIdx.x * 256 + threadIdx.x;
    int grp = tid >> 5;
    int lane = tid & 31;
    int n0 = grp * 16;
    if (n0 >= NN) return;
    int nend = min(n0 + 16, NN);

    float4 acc = make_float4(0.f, 0.f, 0.f, 0.f);
    int gprev = batch[n0];
    for (int n = n0; n < nend; ++n) {
        int g = batch[n];
        if (g != gprev) {
            pool_flush(out, gprev, lane, acc);
            acc = make_float4(0.f, 0.f, 0.f, 0.f);
            gprev = g;
        }
        float4 v = *(const float4*)(h + (size_t)n * DD + lane * 4);
        acc.x += v.x; acc.y += v.y; acc.z += v.z; acc.w += v.w;
    }
    pool_flush(out, gprev, lane, acc);
}

__global__ __launch_bounds__(256) void pool_div_k(float* __restrict__ out,
                                                  const int* __restrict__ cnt)
{
    int tid = blockIdx.x * 256 + threadIdx.x;
    if (tid >= NG * DD) return;
    int g = tid / DD;
    float c = fmaxf((float)cnt[g], 1.0f);
    out[tid] = out[tid] / c;
}

// ---------------------------------------------------------------------------
extern "C" void kernel_launch(void* const* d_in, const int* in_sizes, int n_in,
                              void* d_out, int out_size, void* d_ws, size_t ws_size,
                              hipStream_t stream)
{
    const float* x     = (const float*)d_in[0];
    const float* ea    = (const float*)d_in[1];
    const int*   ei    = (const int*)d_in[2];
    const int*   batch = (const int*)d_in[3];
    const float* w1[4], * b1[4], * w2[4], * b2[4];
    for (int l = 0; l < 4; ++l) {
        w1[l] = (const float*)d_in[4 + 4 * l];
        b1[l] = (const float*)d_in[5 + 4 * l];
        w2[l] = (const float*)d_in[6 + 4 * l];
        b2[l] = (const float*)d_in[7 + 4 * l];
    }

    const int* srcp = ei;            // edge_index[0]
    const int* dstp = ei + NE;       // edge_index[1]

    char* ws = (char*)d_ws;
    const size_t hbytes = (size_t)NN * DD * sizeof(float);   // 20.48 MB
    float* agg = (float*)ws;
    float* hA  = (float*)(ws + hbytes);                      // fallback only
    char*  p   = ws + 2 * hbytes;
    int*  cnt_node = (int*)p;           p += ((NN * 4 + 255) & ~255);
    int*  row_ptr  = (int*)p;           p += (((NN + 1) * 4 + 255) & ~255);
    int*  cursor   = (int*)p;           p += ((NN * 4 + 255) & ~255);
    int2* elist    = (int2*)p;          p += (((size_t)NE * 8 + 255) & ~255);
    int*  srcA     = (int*)p;           p += (((size_t)NE * 4 + 255) & ~255);
    int*  cntG     = (int*)p;           p += 256;
    unsigned short* wt_hi = (unsigned short*)p;  p += (size_t)8 * 16384 * 2;  // 256 KB
    unsigned short* wt_lo = (unsigned short*)p;  p += (size_t)8 * 16384 * 2;  // 256 KB
    unsigned short* hB = (unsigned short*)p;     p += (size_t)NN * DD * 2;    // 10.24 MB
    unsigned short* ea_bf = (unsigned short*)p;
    const size_t need_bf = (size_t)(p - ws) + (size_t)NE * DD * 2;
    const bool use_bf = (ws_size >= need_bf);   // ws_size is call-invariant

    const int eblocks     = (NE + 255) / 256;   // 2500
    const int gblocks     = (NN + 7) / 8;       // 5000
    const int gemm_blocks = NN / 64;            // 625
    const int pool_blocks = ((NN / 16) * 32 + 255) / 256;

    // ---- one-time: memsets + preamble + scan(+bsearch) + fill
    hipMemsetAsync(cnt_node, 0, NN * sizeof(int), stream);
    hipMemsetAsync(d_out, 0, (size_t)NG * DD * sizeof(float), stream);
    if (use_bf)
        preamble_k<1><<<PRE_BLOCKS, 256, 0, stream>>>(
            x, hB, w1[0], w2[0], w1[1], w2[1], w1[2], w2[2], w1[3], w2[3],
            wt_hi, wt_lo, dstp, cnt_node);
    else
        preamble_k<0><<<PRE_BLOCKS, 256, 0, stream>>>(
            x, nullptr, w1[0], w2[0], w1[1], w2[1], w1[2], w2[2], w1[3], w2[3],
            wt_hi, wt_lo, dstp, cnt_node);
    scan_k<<<2, 1024, 0, stream>>>(cnt_node, row_ptr, cursor, batch, cntG);
    fill_k<<<eblocks, 256, 0, stream>>>(srcp, dstp, cursor, elist, srcA);

    if (use_bf) {
        const unsigned short* wh[8];
        const unsigned short* wl[8];
        for (int m = 0; m < 8; ++m) {
            wh[m] = wt_hi + ((size_t)m << 14);
            wl[m] = wt_lo + ((size_t)m << 14);
        }
        for (int l = 0; l < 4; ++l) {
            if (l == 0)
                gather_bf<1><<<gblocks, 256, 0, stream>>>(
                    hB, ea, ea_bf, elist, nullptr, row_ptr, agg);
            else
                gather_bf<0><<<gblocks, 256, 0, stream>>>(
                    hB, nullptr, ea_bf, nullptr, srcA, row_ptr, agg);
            if (l < 3)
                mlp_fused<1><<<gemm_blocks, 256, 0, stream>>>(
                    agg, wh[2 * l], wl[2 * l], b1[l],
                    wh[2 * l + 1], wl[2 * l + 1], b2[l],
                    nullptr, hB, nullptr, nullptr);
            else
                mlp_fused<2><<<gemm_blocks, 256, 0, stream>>>(
                    agg, wh[2 * l], wl[2 * l], b1[l],
                    wh[2 * l + 1], wl[2 * l + 1], b2[l],
                    nullptr, nullptr, (float*)d_out, batch);
        }
    } else {
        const float* hcur = x;
        for (int l = 0; l < 4; ++l) {
            gather_f32<<<gblocks, 256, 0, stream>>>(hcur, ea, row_ptr, elist, agg);
            const unsigned short* h1  = wt_hi + ((size_t)(2 * l) << 14);
            const unsigned short* lo1 = wt_lo + ((size_t)(2 * l) << 14);
            const unsigned short* h2  = wt_hi + ((size_t)(2 * l + 1) << 14);
            const unsigned short* lo2 = wt_lo + ((size_t)(2 * l + 1) << 14);
            mlp_fused<0><<<gemm_blocks, 256, 0, stream>>>(
                agg, h1, lo1, b1[l], h2, lo2, b2[l], hA, nullptr, nullptr, nullptr);
            hcur = hA;
        }
        pool_k<<<pool_blocks, 256, 0, stream>>>(hA, batch, (float*)d_out);
    }

    pool_div_k<<<(NG * DD + 255) / 256, 256, 0, stream>>>((float*)d_out, cntG);
}